// Round 7
// baseline (184.162 us; speedup 1.0000x reference)
//
#include <hip/hip_runtime.h>
#include <cstddef>

// Problem constants
constexpr int NB = 8;      // batch
constexpr int NV = 6;      // views (scan length)
constexpr int NS = 32;     // stochastic dim S
constexpr int ND = 128;    // deter dim D
constexpr int NH = 128;    // hidden H
constexpr int NOBS = 768;  // obs dim

// reduction job space: 12288 f0 wave-jobs + 6144 f1 quad-channel wave-jobs per tensor pair
constexpr int NJOBS = 18432;
constexpr int RWAVES = 8192;   // persistent wave count for reductions

typedef float vf4 __attribute__((ext_vector_type(4)));

__device__ __forceinline__ float sigf(float x) { return 1.0f / (1.0f + expf(-x)); }
__device__ __forceinline__ float siluf(float x) { return x / (1.0f + expf(-x)); }

// -------- shared reducer job (nontemporal streaming loads) --------
// jobs [0, 12288): one f0 channel (704 f4), full-wave coalesced, 11 loads/lane
// jobs [12288, 18432): four consecutive f1 channels (4 x 176 f4); each 16-lane
//   group owns one channel: 176 = 11*16 -> 11 full loads/lane, group reduce.
__device__ __forceinline__ void reduce_job(int wid, int lane,
    const float* __restrict__ f0, const float* __restrict__ f1,
    float* __restrict__ out)
{
    if (wid < 12288) {
        const vf4* s4 = (const vf4*)(f0 + (size_t)wid * 2816);
        vf4 xb[11];
        #pragma unroll
        for (int it = 0; it < 11; it++) xb[it] = __builtin_nontemporal_load(&s4[lane + it * 64]);
        float s = 0.f;
        #pragma unroll
        for (int it = 0; it < 11; it++) s += xb[it].x + xb[it].y + xb[it].z + xb[it].w;
        #pragma unroll
        for (int o = 32; o > 0; o >>= 1) s += __shfl_down(s, o);
        if (lane == 0) {
            int b = wid / 1536, r = wid % 1536, v = r >> 8, c = r & 255;
            out[(size_t)(v * NB + b) * NOBS + c] = s * (1.0f / 2816.0f);
        }
    } else {
        int q = wid - 12288;              // quad index 0..6143
        int g = lane >> 4, sub = lane & 15;
        const vf4* s4 = (const vf4*)(f1 + (size_t)q * 2816);
        vf4 xb[11];
        #pragma unroll
        for (int it = 0; it < 11; it++) xb[it] = __builtin_nontemporal_load(&s4[g * 176 + sub + it * 16]);
        float s = 0.f;
        #pragma unroll
        for (int it = 0; it < 11; it++) s += xb[it].x + xb[it].y + xb[it].z + xb[it].w;
        #pragma unroll
        for (int o = 8; o > 0; o >>= 1) s += __shfl_down(s, o, 16);
        if (sub == 0) {
            int c4 = 4 * q + g;           // f1 channel 0..24575
            int b = c4 / 3072, r = c4 % 3072, v = r >> 9, c = r & 511;
            out[(size_t)(v * NB + b) * NOBS + 256 + c] = s * (1.0f / 704.0f);
        }
    }
}

// -------- Kernel 1: BOTH feature-mean reductions (386 MB, NT streaming) --------
__global__ __launch_bounds__(256) void reduce_all(
    const float* __restrict__ sf0, const float* __restrict__ sf1,
    const float* __restrict__ tf0, const float* __restrict__ tf1,
    float* __restrict__ obs, float* __restrict__ tgt)
{
    int lane = threadIdx.x & 63;
    int w0 = blockIdx.x * 4 + (threadIdx.x >> 6);
    for (int wid = w0; wid < 2 * NJOBS; wid += RWAVES) {
        if (wid < NJOBS) reduce_job(wid, lane, sf0, sf1, obs);
        else             reduce_job(wid - NJOBS, lane, tf0, tf1, tgt);
    }
}

// -------- Kernel 2: encoder (blocks 0-47) + mask prep (block 48) + L3 warm (49-64)
__global__ __launch_bounds__(512) void encoder(
    const float* __restrict__ obs,
    const float* __restrict__ w1, const float* __restrict__ b1,
    const float* __restrict__ g, const float* __restrict__ be,
    const float* __restrict__ w2, const float* __restrict__ b2,
    float* __restrict__ obs_embed,
    const void* cam, float* __restrict__ maskf,
    const float* __restrict__ prior_w1, const float* __restrict__ post_w1,
    const float* __restrict__ prior_w2, const float* __restrict__ post_w2,
    const float* __restrict__ gru_wih,  const float* __restrict__ gru_whh,
    float* __restrict__ warm_dummy)
{
    int tid = threadIdx.x;    // 0..511

    if (blockIdx.x == 48) {
        // mask prep (detect int32 vs byte bool layout)
        if (tid != 0) return;
        const int* wi = (const int*)cam;
        bool is_i32 = true;
        for (int i = 0; i < NB * NV; i++) {
            unsigned v = (unsigned)wi[i];
            if (v > 1u) { is_i32 = false; break; }
        }
        const unsigned char* wb = (const unsigned char*)cam;
        for (int b = 0; b < NB; b++)
            for (int v = 0; v < NV; v++) {
                int val = is_i32 ? wi[b * NV + v] : (int)wb[b * NV + v];
                maskf[v * NB + b] = val ? 1.0f : 0.0f;
            }
        return;
    }
    if (blockIdx.x > 48) {
        // warm the scan's weight set into L3 (reads must survive DCE)
        int wtid = (blockIdx.x - 49) * 512 + tid;    // 0..8191
        const float* arrs[6] = {prior_w1, post_w1, prior_w2, post_w2, gru_wih, gru_whh};
        const int n4s[6] = {4096, 8192, 2048, 2048, 3072, 12288};  // float4 counts
        float s = 0.f;
        for (int a = 0; a < 6; a++) {
            const vf4* p = (const vf4*)arrs[a];
            int n4 = n4s[a];
            for (int i = wtid; i < n4; i += 16 * 512) {
                vf4 x = p[i];
                s += x.x + x.y + x.z + x.w;
            }
        }
        warm_dummy[wtid & 63] = s;   // reserved scratch slot; keeps loads live
        return;
    }

    __shared__ float xs[NOBS];
    __shared__ float hs[NH];
    __shared__ float pE[4][NH];
    __shared__ float red[2], red2[2];
    int r = blockIdx.x;       // r = v*NB + b
    const float* row = obs + (size_t)r * NOBS;
    for (int i = tid; i < NOBS; i += 512) xs[i] = row[i];
    __syncthreads();

    // layer 1: 128 outs x K=768, 4-way split (192 each)
    {
        int part = tid >> 7, j = tid & 127;
        int k0 = part * 192;
        float a = 0.0f;
        #pragma unroll 8
        for (int k = k0; k < k0 + 192; k++) a += xs[k] * w1[k * NH + j];
        pE[part][j] = a;
    }
    __syncthreads();

    float a1 = 0.0f;
    if (tid < NH) {
        a1 = b1[tid] + pE[0][tid] + pE[1][tid] + pE[2][tid] + pE[3][tid];
        float v = a1;
        for (int o = 32; o > 0; o >>= 1) v += __shfl_down(v, o);
        if ((tid & 63) == 0) red[tid >> 6] = v;
    }
    __syncthreads();
    if (tid < NH) {
        float mu = (red[0] + red[1]) * (1.0f / 128.0f);
        float d = a1 - mu;
        float dv = d * d;
        for (int o = 32; o > 0; o >>= 1) dv += __shfl_down(dv, o);
        if ((tid & 63) == 0) red2[tid >> 6] = dv;
    }
    __syncthreads();
    if (tid < NH) {
        float mu = (red[0] + red[1]) * (1.0f / 128.0f);
        float var = (red2[0] + red2[1]) * (1.0f / 128.0f);
        float xn = (a1 - mu) * rsqrtf(var + 1e-5f) * g[tid] + be[tid];
        hs[tid] = siluf(xn);
    }
    __syncthreads();

    // layer 2: 128 outs x K=128, 4-way split (32 each)
    {
        int part = tid >> 7, j = tid & 127;
        int k0 = part * 32;
        float a = 0.0f;
        #pragma unroll 8
        for (int k = k0; k < k0 + 32; k++) a += hs[k] * w2[k * NH + j];
        pE[part][j] = a;
    }
    __syncthreads();
    if (tid < NH) {
        float a = b2[tid] + pE[0][tid] + pE[1][tid] + pE[2][tid] + pE[3][tid];
        obs_embed[(size_t)r * NH + tid] = siluf(a);
    }
}

// -------- Kernel 3: RSSM scan ALONE (8 blocks, wb[8] ping-pong, no spill) --------
__global__ __launch_bounds__(512) void scan_only(
    const float* __restrict__ obs_embed,
    const float* __restrict__ maskf,
    const float* __restrict__ eps_prior, const float* __restrict__ eps_post,
    const float* __restrict__ prior_w1, const float* __restrict__ prior_b1,
    const float* __restrict__ prior_w2, const float* __restrict__ prior_b2,
    const float* __restrict__ post_w1, const float* __restrict__ post_b1,
    const float* __restrict__ post_w2, const float* __restrict__ post_b2,
    const float* __restrict__ gru_wih, const float* __restrict__ gru_whh,
    const float* __restrict__ gru_bih, const float* __restrict__ gru_bhh,
    float* __restrict__ deter_all, float* __restrict__ z_all,
    float* __restrict__ kl_out)
{
    __shared__ float pbuf[2048];         // 512 float4 split-K partials
    __shared__ float gi_s[3 * ND];
    __shared__ float deter[ND], obs_e[NH], t1[NH], t2[NH];
    __shared__ float pmu[NS], plv[NS], qmu[NS], qlv[NS], zsm[NS];
    vf4* pbuf4 = (vf4*)pbuf;

    int b = blockIdx.x;       // 0..7
    int tid = threadIdx.x;    // 0..511

    if (tid < ND) deter[tid] = 0.0f;
    __syncthreads();

    for (int t = 0; t < NV; t++) {
        int rb = t * NB + b;
        if (tid < NH) obs_e[tid] = obs_embed[(size_t)rb * NH + tid];
        __syncthreads();

        // ---- Phase A: prior hidden (thr 0-255, K=128) | post hidden (thr 256-511, K=256)
        if (tid < 256) {
            int g = tid & 31, part = tid >> 5;   // 32 groups x 8 parts x 16 rows
            int k0 = part * 16;
            const vf4* w = (const vf4*)prior_w1; // [128][32 f4]
            vf4 wb0[8], wb1[8];
            #pragma unroll
            for (int i = 0; i < 8; i++) wb0[i] = w[(k0 + i) * 32 + g];
            #pragma unroll
            for (int i = 0; i < 8; i++) wb1[i] = w[(k0 + 8 + i) * 32 + g];
            vf4 acc = {0.f, 0.f, 0.f, 0.f};
            #pragma unroll
            for (int i = 0; i < 8; i++) acc += deter[k0 + i] * wb0[i];
            #pragma unroll
            for (int i = 0; i < 8; i++) acc += deter[k0 + 8 + i] * wb1[i];
            pbuf4[part * 32 + g] = acc;
        } else {
            int u = tid - 256;
            int g = u & 31, part = u >> 5;       // 32 groups x 8 parts x 32 rows
            int k0 = part * 32;
            const vf4* w = (const vf4*)post_w1;  // [256][32 f4]
            vf4 wb0[8], wb1[8];
            vf4 acc = {0.f, 0.f, 0.f, 0.f};
            #pragma unroll
            for (int i = 0; i < 8; i++) wb0[i] = w[(k0 + i) * 32 + g];
            #pragma unroll
            for (int i = 0; i < 8; i++) wb1[i] = w[(k0 + 8 + i) * 32 + g];
            #pragma unroll
            for (int i = 0; i < 8; i++) {
                int k = k0 + i;
                acc += ((k < ND) ? deter[k] : obs_e[k - ND]) * wb0[i];
            }
            #pragma unroll
            for (int i = 0; i < 8; i++) wb0[i] = w[(k0 + 16 + i) * 32 + g];
            #pragma unroll
            for (int i = 0; i < 8; i++) {
                int k = k0 + 8 + i;
                acc += ((k < ND) ? deter[k] : obs_e[k - ND]) * wb1[i];
            }
            #pragma unroll
            for (int i = 0; i < 8; i++) wb1[i] = w[(k0 + 24 + i) * 32 + g];
            #pragma unroll
            for (int i = 0; i < 8; i++) {
                int k = k0 + 16 + i;
                acc += ((k < ND) ? deter[k] : obs_e[k - ND]) * wb0[i];
            }
            #pragma unroll
            for (int i = 0; i < 8; i++) {
                int k = k0 + 24 + i;
                acc += ((k < ND) ? deter[k] : obs_e[k - ND]) * wb1[i];
            }
            pbuf4[256 + part * 32 + g] = acc;
        }
        __syncthreads();
        if (tid < 256) {
            int j = tid;
            float a = 0.0f;
            if (j < NH) {
                int g = j >> 2, c = j & 3;
                #pragma unroll
                for (int p = 0; p < 8; p++) a += pbuf[(p * 32 + g) * 4 + c];
                t1[j] = siluf(a + prior_b1[j]);
            } else {
                int jj = j - NH;
                int g = jj >> 2, c = jj & 3;
                #pragma unroll
                for (int p = 0; p < 8; p++) a += pbuf[(256 + p * 32 + g) * 4 + c];
                t2[jj] = siluf(a + post_b1[jj]);
            }
        }
        __syncthreads();

        // ---- Phase B: prior2 | post2, K=128, 16 parts x 8 rows, single wb[8]
        {
            bool isPrior = tid < 256;
            int u = isPrior ? tid : tid - 256;
            int g = u & 15, part = u >> 4;
            int k0 = part * 8;
            const vf4* w = (const vf4*)(isPrior ? prior_w2 : post_w2);   // [128][16 f4]
            const float* act = isPrior ? t1 : t2;
            vf4 wb[8];
            #pragma unroll
            for (int i = 0; i < 8; i++) wb[i] = w[(k0 + i) * 16 + g];
            vf4 acc = {0.f, 0.f, 0.f, 0.f};
            #pragma unroll
            for (int i = 0; i < 8; i++) acc += act[k0 + i] * wb[i];
            pbuf4[(isPrior ? 0 : 256) + part * 16 + g] = acc;
        }
        __syncthreads();
        if (tid < 128) {
            int j = tid;
            float a = 0.0f;
            if (j < 64) {
                int g = j >> 2, c = j & 3;
                #pragma unroll
                for (int p = 0; p < 16; p++) a += pbuf[(p * 16 + g) * 4 + c];
                a += prior_b2[j];
                if (j < NS) pmu[j] = a; else plv[j - NS] = a;
            } else {
                int jj = j - 64;
                int g = jj >> 2, c = jj & 3;
                #pragma unroll
                for (int p = 0; p < 16; p++) a += pbuf[(256 + p * 16 + g) * 4 + c];
                a += post_b2[jj];
                if (jj < NS) qmu[jj] = a; else qlv[jj - NS] = a;
            }
        }
        __syncthreads();

        // ---- Phase C: z sample + KL
        if (tid < NS) {
            float m = maskf[rb];
            float zp = pmu[tid] + eps_prior[(size_t)rb * NS + tid] * expf(0.5f * plv[tid]);
            float zq = qmu[tid] + eps_post[(size_t)rb * NS + tid] * expf(0.5f * qlv[tid]);
            float z = (m > 0.0f) ? zp : zq;
            zsm[tid] = z;
            z_all[(size_t)rb * NS + tid] = z;
            float vq = fmaxf(expf(qlv[tid]), 1e-5f);
            float vp = fmaxf(expf(plv[tid]), 1e-5f);
            float dm = qmu[tid] - pmu[tid];
            float kle = 0.5f * ((vq + dm * dm) / vp - 1.0f + plv[tid] - qlv[tid]);
            for (int o = 16; o > 0; o >>= 1) kle += __shfl_down(kle, o, 32);
            if (tid == 0) kl_out[rb] = kle;
        }
        __syncthreads();

        // ---- Phase D: gi (thr 0-95, K=32) + gh (thr 128-511, 4 parts x 32 rows)
        if (tid < 96) {
            int g = tid;   // 96 f4 groups over 384 outs
            const vf4* w = (const vf4*)gru_wih;    // [32][96 f4]
            vf4 wb0[8], wb1[8];
            vf4 acc = {0.f, 0.f, 0.f, 0.f};
            #pragma unroll
            for (int i = 0; i < 8; i++) wb0[i] = w[i * 96 + g];
            #pragma unroll
            for (int i = 0; i < 8; i++) wb1[i] = w[(8 + i) * 96 + g];
            #pragma unroll
            for (int i = 0; i < 8; i++) acc += zsm[i] * wb0[i];
            #pragma unroll
            for (int i = 0; i < 8; i++) wb0[i] = w[(16 + i) * 96 + g];
            #pragma unroll
            for (int i = 0; i < 8; i++) acc += zsm[8 + i] * wb1[i];
            #pragma unroll
            for (int i = 0; i < 8; i++) wb1[i] = w[(24 + i) * 96 + g];
            #pragma unroll
            for (int i = 0; i < 8; i++) acc += zsm[16 + i] * wb0[i];
            #pragma unroll
            for (int i = 0; i < 8; i++) acc += zsm[24 + i] * wb1[i];
            gi_s[4 * g + 0] = acc.x + gru_bih[4 * g + 0];
            gi_s[4 * g + 1] = acc.y + gru_bih[4 * g + 1];
            gi_s[4 * g + 2] = acc.z + gru_bih[4 * g + 2];
            gi_s[4 * g + 3] = acc.w + gru_bih[4 * g + 3];
        } else if (tid >= 128) {
            int u = tid - 128;               // 0..383
            int g = u % 96, part = u / 96;   // 96 groups x 4 parts x 32 rows
            int k0 = part * 32;
            const vf4* w = (const vf4*)gru_whh;    // [128][96 f4]
            vf4 wb0[8], wb1[8];
            vf4 acc = {0.f, 0.f, 0.f, 0.f};
            #pragma unroll
            for (int i = 0; i < 8; i++) wb0[i] = w[(k0 + i) * 96 + g];
            #pragma unroll
            for (int i = 0; i < 8; i++) wb1[i] = w[(k0 + 8 + i) * 96 + g];
            #pragma unroll
            for (int i = 0; i < 8; i++) acc += deter[k0 + i] * wb0[i];
            #pragma unroll
            for (int i = 0; i < 8; i++) wb0[i] = w[(k0 + 16 + i) * 96 + g];
            #pragma unroll
            for (int i = 0; i < 8; i++) acc += deter[k0 + 8 + i] * wb1[i];
            #pragma unroll
            for (int i = 0; i < 8; i++) wb1[i] = w[(k0 + 24 + i) * 96 + g];
            #pragma unroll
            for (int i = 0; i < 8; i++) acc += deter[k0 + 16 + i] * wb0[i];
            #pragma unroll
            for (int i = 0; i < 8; i++) acc += deter[k0 + 24 + i] * wb1[i];
            pbuf4[part * 96 + g] = acc;
        }
        __syncthreads();

        // ---- Phase E: GRU combine + deter update
        if (tid < ND) {
            int j = tid;
            int gr = j >> 2, c = j & 3;
            float hr = gru_bhh[j], hz = gru_bhh[ND + j], hn = gru_bhh[2 * ND + j];
            #pragma unroll
            for (int p = 0; p < 4; p++) {
                hr += pbuf[(p * 96 + gr) * 4 + c];
                hz += pbuf[(p * 96 + 32 + gr) * 4 + c];
                hn += pbuf[(p * 96 + 64 + gr) * 4 + c];
            }
            float r = sigf(gi_s[j] + hr);
            float u = sigf(gi_s[ND + j] + hz);
            float n = tanhf(gi_s[2 * ND + j] + r * hn);
            float dn = (1.0f - u) * n + u * deter[j];
            deter[j] = dn;
            deter_all[(size_t)rb * ND + j] = dn;
        }
        __syncthreads();
    }
}

// -------- Kernel 4: decoder + recon MSE, 48-way parallel --------
__global__ __launch_bounds__(512) void decoder_kernel(
    const float* __restrict__ deter_all, const float* __restrict__ z_all,
    const float* __restrict__ tgt,
    const float* __restrict__ dec_w1, const float* __restrict__ dec_b1,
    const float* __restrict__ dec_w2, const float* __restrict__ dec_b2,
    float* __restrict__ recon_out)
{
    int rb = blockIdx.x;      // 0..47
    int tid = threadIdx.x;    // 0..511
    __shared__ float din[ND + NS];   // 160
    __shared__ float d1[NH];
    __shared__ float p1[4][NH];
    __shared__ float redb[8];

    if (tid < ND) din[tid] = deter_all[(size_t)rb * ND + tid];
    else if (tid < ND + NS) din[tid] = z_all[(size_t)rb * NS + (tid - ND)];
    __syncthreads();

    // dec layer 1: 128 outs x K=160, 4-way split (40 each)
    {
        int part = tid >> 7, j = tid & 127;
        int k0 = part * 40;
        float a = 0.0f;
        #pragma unroll 8
        for (int k = k0; k < k0 + 40; k++) a += din[k] * dec_w1[k * NH + j];
        p1[part][j] = a;
    }
    __syncthreads();
    if (tid < NH) {
        float a = dec_b1[tid] + p1[0][tid] + p1[1][tid] + p1[2][tid] + p1[3][tid];
        d1[tid] = siluf(a);
    }
    __syncthreads();

    // dec layer 2 + MSE
    float se = 0.0f;
    const float* trow = tgt + (size_t)rb * NOBS;
    for (int o = tid; o < NOBS; o += 512) {
        float a = dec_b2[o];
        #pragma unroll 8
        for (int i = 0; i < NH; i++) a += d1[i] * dec_w2[i * NOBS + o];
        float df = a - trow[o];
        se += df * df;
    }
    for (int o = 32; o > 0; o >>= 1) se += __shfl_down(se, o);
    if ((tid & 63) == 0) redb[tid >> 6] = se;
    __syncthreads();
    if (tid == 0) {
        float s = 0.0f;
        for (int p = 0; p < 8; p++) s += redb[p];
        recon_out[rb] = s * (1.0f / 768.0f);
    }
}

// -------- Kernel 5: finalize (mask-weighted scalar combine) --------
__global__ void finalize(const float* __restrict__ maskf,
                         const float* __restrict__ recon,
                         const float* __restrict__ kl,
                         float* __restrict__ out)
{
    if (threadIdx.x != 0 || blockIdx.x != 0) return;
    float rl = 0.0f, rs = 0.0f, ka = 0.0f, kn = 0.0f;
    for (int t = 0; t < NV; t++) {
        float ms = 0.0f, rsum = 0.0f, osum = 0.0f, ksum = 0.0f;
        for (int b = 0; b < NB; b++) {
            float m = maskf[t * NB + b];
            ms += m;
            rsum += recon[t * NB + b] * m;
            osum += 1.0f - m;
            ksum += kl[t * NB + b] * (1.0f - m);
        }
        if (ms > 0.0f) { rl += rsum / fmaxf(ms, 1.0f); rs += 1.0f; }
        if (osum > 0.0f) { ka += ksum / fmaxf(osum, 1.0f); kn += 1.0f; }
    }
    out[0] = rl / fmaxf(rs, 1.0f);
    out[1] = (ka / fmaxf(kn, 1.0f)) * 1e-4f;
}

extern "C" void kernel_launch(void* const* d_in, const int* in_sizes, int n_in,
                              void* d_out, int out_size, void* d_ws, size_t ws_size,
                              hipStream_t stream) {
    const float* sf0 = (const float*)d_in[0];
    const float* sf1 = (const float*)d_in[1];
    const float* tf0 = (const float*)d_in[2];
    const float* tf1 = (const float*)d_in[3];
    const void*  cam = d_in[4];
    const float* eps_prior = (const float*)d_in[5];
    const float* eps_post  = (const float*)d_in[6];
    const float* enc_w1 = (const float*)d_in[7];
    const float* enc_b1 = (const float*)d_in[8];
    const float* ln_g   = (const float*)d_in[9];
    const float* ln_b   = (const float*)d_in[10];
    const float* enc_w2 = (const float*)d_in[11];
    const float* enc_b2 = (const float*)d_in[12];
    const float* prior_w1 = (const float*)d_in[13];
    const float* prior_b1 = (const float*)d_in[14];
    const float* prior_w2 = (const float*)d_in[15];
    const float* prior_b2 = (const float*)d_in[16];
    const float* post_w1 = (const float*)d_in[17];
    const float* post_b1 = (const float*)d_in[18];
    const float* post_w2 = (const float*)d_in[19];
    const float* post_b2 = (const float*)d_in[20];
    const float* dec_w1 = (const float*)d_in[21];
    const float* dec_b1 = (const float*)d_in[22];
    const float* dec_w2 = (const float*)d_in[23];
    const float* dec_b2 = (const float*)d_in[24];
    const float* gru_wih = (const float*)d_in[25];
    const float* gru_whh = (const float*)d_in[26];
    const float* gru_bih = (const float*)d_in[27];
    const float* gru_bhh = (const float*)d_in[28];

    float* ws = (float*)d_ws;
    float* obs   = ws;                 // 48*768 = 36864
    float* tgt   = ws + 36864;         // 36864
    float* oe    = ws + 73728;         // 48*128 = 6144
    float* maskf = ws + 79872;         // 48
    float* rec   = ws + 79920;         // 48
    float* klv   = ws + 79968;         // 48
    float* deter_all = ws + 80016;     // 48*128 = 6144
    float* z_all     = ws + 86160;     // 48*32  = 1536
    float* warm_dummy = ws + 87696;    // 64

    // both reductions in one streaming kernel: 2048 blocks x 256 = 8192 waves
    reduce_all<<<RWAVES / 4, 256, 0, stream>>>(sf0, sf1, tf0, tf1, obs, tgt);
    // encoder + mask prep + weight warm
    encoder<<<65, 512, 0, stream>>>(obs, enc_w1, enc_b1, ln_g, ln_b, enc_w2, enc_b2, oe,
                                    cam, maskf,
                                    prior_w1, post_w1, prior_w2, post_w2, gru_wih, gru_whh,
                                    warm_dummy);
    scan_only<<<8, 512, 0, stream>>>(oe, maskf, eps_prior, eps_post,
                                     prior_w1, prior_b1, prior_w2, prior_b2,
                                     post_w1, post_b1, post_w2, post_b2,
                                     gru_wih, gru_whh, gru_bih, gru_bhh,
                                     deter_all, z_all, klv);
    decoder_kernel<<<48, 512, 0, stream>>>(deter_all, z_all, tgt,
                                           dec_w1, dec_b1, dec_w2, dec_b2, rec);
    finalize<<<1, 64, 0, stream>>>(maskf, rec, klv, (float*)d_out);
}

// Round 8
// 154.831 us; speedup vs baseline: 1.1894x; 1.1894x over previous
//
#include <hip/hip_runtime.h>
#include <cstddef>

// Problem constants
constexpr int NB = 8;      // batch
constexpr int NV = 6;      // views (scan length)
constexpr int NS = 32;     // stochastic dim S
constexpr int ND = 128;    // deter dim D
constexpr int NH = 128;    // hidden H
constexpr int NOBS = 768;  // obs dim

// reduction job space: 12288 f0 wave-jobs + 6144 f1 quad-channel wave-jobs per tensor pair
constexpr int NJOBS = 18432;
constexpr int RWAVES = 8192;   // persistent wave count for reductions

typedef float vf4 __attribute__((ext_vector_type(4)));

__device__ __forceinline__ float sigf(float x) { return 1.0f / (1.0f + expf(-x)); }
__device__ __forceinline__ float siluf(float x) { return x / (1.0f + expf(-x)); }

// ---- double-buffered K-dot: NB8 batches of 8 rows, 8 loads always in flight ----
// All indices compile-time after unroll: no dynamic local indexing (no scratch).
template<int NB8>
__device__ __forceinline__ vf4 dotk(const vf4* __restrict__ w, int ldg, int g, int k0,
                                    const float* __restrict__ x) {
    vf4 acc = {0.f, 0.f, 0.f, 0.f};
    vf4 wa[8], wb[8];
    #pragma unroll
    for (int i = 0; i < 8; i++) wa[i] = w[(size_t)(k0 + i) * ldg + g];
    #pragma unroll
    for (int bb = 0; bb < NB8; bb++) {
        int kb = k0 + bb * 8;
        if ((bb & 1) == 0) {
            if (bb + 1 < NB8) {
                #pragma unroll
                for (int i = 0; i < 8; i++) wb[i] = w[(size_t)(kb + 8 + i) * ldg + g];
            }
            #pragma unroll
            for (int i = 0; i < 8; i++) acc += x[kb + i] * wa[i];
        } else {
            if (bb + 1 < NB8) {
                #pragma unroll
                for (int i = 0; i < 8; i++) wa[i] = w[(size_t)(kb + 8 + i) * ldg + g];
            }
            #pragma unroll
            for (int i = 0; i < 8; i++) acc += x[kb + i] * wb[i];
        }
    }
    return acc;
}

// -------- shared reducer job (nontemporal streaming loads) --------
__device__ __forceinline__ void reduce_job(int wid, int lane,
    const float* __restrict__ f0, const float* __restrict__ f1,
    float* __restrict__ out)
{
    if (wid < 12288) {
        const vf4* s4 = (const vf4*)(f0 + (size_t)wid * 2816);
        vf4 xb[11];
        #pragma unroll
        for (int it = 0; it < 11; it++) xb[it] = __builtin_nontemporal_load(&s4[lane + it * 64]);
        float s = 0.f;
        #pragma unroll
        for (int it = 0; it < 11; it++) s += xb[it].x + xb[it].y + xb[it].z + xb[it].w;
        #pragma unroll
        for (int o = 32; o > 0; o >>= 1) s += __shfl_down(s, o);
        if (lane == 0) {
            int b = wid / 1536, r = wid % 1536, v = r >> 8, c = r & 255;
            out[(size_t)(v * NB + b) * NOBS + c] = s * (1.0f / 2816.0f);
        }
    } else {
        int q = wid - 12288;              // quad index 0..6143
        int g = lane >> 4, sub = lane & 15;
        const vf4* s4 = (const vf4*)(f1 + (size_t)q * 2816);
        vf4 xb[11];
        #pragma unroll
        for (int it = 0; it < 11; it++) xb[it] = __builtin_nontemporal_load(&s4[g * 176 + sub + it * 16]);
        float s = 0.f;
        #pragma unroll
        for (int it = 0; it < 11; it++) s += xb[it].x + xb[it].y + xb[it].z + xb[it].w;
        #pragma unroll
        for (int o = 8; o > 0; o >>= 1) s += __shfl_down(s, o, 16);
        if (sub == 0) {
            int c4 = 4 * q + g;           // f1 channel 0..24575
            int b = c4 / 3072, r = c4 % 3072, v = r >> 9, c = r & 511;
            out[(size_t)(v * NB + b) * NOBS + 256 + c] = s * (1.0f / 704.0f);
        }
    }
}

// -------- Kernel 1: BOTH feature-mean reductions (386 MB, NT streaming) --------
__global__ __launch_bounds__(256) void reduce_all(
    const float* __restrict__ sf0, const float* __restrict__ sf1,
    const float* __restrict__ tf0, const float* __restrict__ tf1,
    float* __restrict__ obs, float* __restrict__ tgt)
{
    int lane = threadIdx.x & 63;
    int w0 = blockIdx.x * 4 + (threadIdx.x >> 6);
    for (int wid = w0; wid < 2 * NJOBS; wid += RWAVES) {
        if (wid < NJOBS) reduce_job(wid, lane, sf0, sf1, obs);
        else             reduce_job(wid - NJOBS, lane, tf0, tf1, tgt);
    }
}

// -------- Kernel 2: encoder (blocks 0-47) + mask prep (block 48) + L3 warm (49-64)
__global__ __launch_bounds__(512) void encoder(
    const float* __restrict__ obs,
    const float* __restrict__ w1, const float* __restrict__ b1,
    const float* __restrict__ g, const float* __restrict__ be,
    const float* __restrict__ w2, const float* __restrict__ b2,
    float* __restrict__ obs_embed,
    const void* cam, float* __restrict__ maskf,
    const float* __restrict__ prior_w1, const float* __restrict__ post_w1,
    const float* __restrict__ prior_w2, const float* __restrict__ post_w2,
    const float* __restrict__ gru_wih,  const float* __restrict__ gru_whh,
    float* __restrict__ warm_dummy)
{
    int tid = threadIdx.x;    // 0..511

    if (blockIdx.x == 48) {
        if (tid != 0) return;
        const int* wi = (const int*)cam;
        bool is_i32 = true;
        for (int i = 0; i < NB * NV; i++) {
            unsigned v = (unsigned)wi[i];
            if (v > 1u) { is_i32 = false; break; }
        }
        const unsigned char* wb = (const unsigned char*)cam;
        for (int b = 0; b < NB; b++)
            for (int v = 0; v < NV; v++) {
                int val = is_i32 ? wi[b * NV + v] : (int)wb[b * NV + v];
                maskf[v * NB + b] = val ? 1.0f : 0.0f;
            }
        return;
    }
    if (blockIdx.x > 48) {
        // warm the scan's weight set into L3
        int wtid = (blockIdx.x - 49) * 512 + tid;    // 0..8191
        const float* arrs[6] = {prior_w1, post_w1, prior_w2, post_w2, gru_wih, gru_whh};
        const int n4s[6] = {4096, 8192, 2048, 2048, 3072, 12288};  // float4 counts
        float s = 0.f;
        for (int a = 0; a < 6; a++) {
            const vf4* p = (const vf4*)arrs[a];
            int n4 = n4s[a];
            for (int i = wtid; i < n4; i += 16 * 512) {
                vf4 x = p[i];
                s += x.x + x.y + x.z + x.w;
            }
        }
        warm_dummy[wtid & 63] = s;
        return;
    }

    __shared__ float xs[NOBS];
    __shared__ float hs[NH];
    __shared__ float pE[4][NH];
    __shared__ float red[2], red2[2];
    int r = blockIdx.x;       // r = v*NB + b
    const float* row = obs + (size_t)r * NOBS;
    for (int i = tid; i < NOBS; i += 512) xs[i] = row[i];
    __syncthreads();

    {
        int part = tid >> 7, j = tid & 127;
        int k0 = part * 192;
        float a = 0.0f;
        #pragma unroll 8
        for (int k = k0; k < k0 + 192; k++) a += xs[k] * w1[k * NH + j];
        pE[part][j] = a;
    }
    __syncthreads();

    float a1 = 0.0f;
    if (tid < NH) {
        a1 = b1[tid] + pE[0][tid] + pE[1][tid] + pE[2][tid] + pE[3][tid];
        float v = a1;
        for (int o = 32; o > 0; o >>= 1) v += __shfl_down(v, o);
        if ((tid & 63) == 0) red[tid >> 6] = v;
    }
    __syncthreads();
    if (tid < NH) {
        float mu = (red[0] + red[1]) * (1.0f / 128.0f);
        float d = a1 - mu;
        float dv = d * d;
        for (int o = 32; o > 0; o >>= 1) dv += __shfl_down(dv, o);
        if ((tid & 63) == 0) red2[tid >> 6] = dv;
    }
    __syncthreads();
    if (tid < NH) {
        float mu = (red[0] + red[1]) * (1.0f / 128.0f);
        float var = (red2[0] + red2[1]) * (1.0f / 128.0f);
        float xn = (a1 - mu) * rsqrtf(var + 1e-5f) * g[tid] + be[tid];
        hs[tid] = siluf(xn);
    }
    __syncthreads();

    {
        int part = tid >> 7, j = tid & 127;
        int k0 = part * 32;
        float a = 0.0f;
        #pragma unroll 8
        for (int k = k0; k < k0 + 32; k++) a += hs[k] * w2[k * NH + j];
        pE[part][j] = a;
    }
    __syncthreads();
    if (tid < NH) {
        float a = b2[tid] + pE[0][tid] + pE[1][tid] + pE[2][tid] + pE[3][tid];
        obs_embed[(size_t)r * NH + tid] = siluf(a);
    }
}

// -------- Kernel 3: RSSM scan, 256 threads/block (VGPR cap 256 -> no spill) --------
__global__ __launch_bounds__(256) void scan_only(
    const float* __restrict__ obs_embed,
    const float* __restrict__ maskf,
    const float* __restrict__ eps_prior, const float* __restrict__ eps_post,
    const float* __restrict__ prior_w1, const float* __restrict__ prior_b1,
    const float* __restrict__ prior_w2, const float* __restrict__ prior_b2,
    const float* __restrict__ post_w1, const float* __restrict__ post_b1,
    const float* __restrict__ post_w2, const float* __restrict__ post_b2,
    const float* __restrict__ gru_wih, const float* __restrict__ gru_whh,
    const float* __restrict__ gru_bih, const float* __restrict__ gru_bhh,
    float* __restrict__ deter_all, float* __restrict__ z_all,
    float* __restrict__ kl_out)
{
    __shared__ float pbuf[1024];         // 256 float4 split-K partials
    __shared__ float gi_s[3 * ND];
    __shared__ float deter_obs[ND + NH]; // deter [0,128), obs_e [128,256)
    __shared__ float t12[2 * NH];        // t1 [0,128), t2 [128,256)
    __shared__ float pmu[NS], plv[NS], qmu[NS], qlv[NS], zsm[NS];
    vf4* pbuf4 = (vf4*)pbuf;
    float* deter = deter_obs;

    int b = blockIdx.x;       // 0..7
    int tid = threadIdx.x;    // 0..255

    if (tid < ND) deter[tid] = 0.0f;
    __syncthreads();

    for (int t = 0; t < NV; t++) {
        int rb = t * NB + b;
        if (tid < NH) deter_obs[ND + tid] = obs_embed[(size_t)rb * NH + tid];
        __syncthreads();

        // ---- Phase A: prior hidden (tid<128: 32g x 4p x 32rows, K=128)
        //               post hidden  (tid>=128: 32g x 4p x 64rows, K=256)
        if (tid < 128) {
            int g = tid & 31, part = tid >> 5;
            vf4 acc = dotk<4>((const vf4*)prior_w1, 32, g, part * 32, deter);
            pbuf4[part * 32 + g] = acc;
        } else {
            int u = tid - 128;
            int g = u & 31, part = u >> 5;
            vf4 acc = dotk<8>((const vf4*)post_w1, 32, g, part * 64, deter_obs);
            pbuf4[128 + part * 32 + g] = acc;
        }
        __syncthreads();
        {
            int j = tid;
            float a = 0.0f;
            if (j < NH) {
                int g = j >> 2, c = j & 3;
                #pragma unroll
                for (int p = 0; p < 4; p++) a += pbuf[(p * 32 + g) * 4 + c];
                t12[j] = siluf(a + prior_b1[j]);
            } else {
                int jj = j - NH;
                int g = jj >> 2, c = jj & 3;
                #pragma unroll
                for (int p = 0; p < 4; p++) a += pbuf[(128 + p * 32 + g) * 4 + c];
                t12[NH + jj] = siluf(a + post_b1[jj]);
            }
        }
        __syncthreads();

        // ---- Phase B: prior2 (tid<128) | post2 (tid>=128), 16g x 8p x 16rows, K=128
        {
            bool isPrior = tid < 128;
            int u = isPrior ? tid : tid - 128;
            int g = u & 15, part = u >> 4;
            const vf4* w = (const vf4*)(isPrior ? prior_w2 : post_w2);   // [128][16 f4]
            const float* act = t12 + (isPrior ? 0 : NH);
            vf4 acc = dotk<2>(w, 16, g, part * 16, act);
            pbuf4[(isPrior ? 0 : 128) + part * 16 + g] = acc;
        }
        __syncthreads();
        if (tid < 128) {
            int j = tid;
            float a = 0.0f;
            if (j < 64) {
                int g = j >> 2, c = j & 3;
                #pragma unroll
                for (int p = 0; p < 8; p++) a += pbuf[(p * 16 + g) * 4 + c];
                a += prior_b2[j];
                if (j < NS) pmu[j] = a; else plv[j - NS] = a;
            } else {
                int jj = j - 64;
                int g = jj >> 2, c = jj & 3;
                #pragma unroll
                for (int p = 0; p < 8; p++) a += pbuf[(128 + p * 16 + g) * 4 + c];
                a += post_b2[jj];
                if (jj < NS) qmu[jj] = a; else qlv[jj - NS] = a;
            }
        }
        __syncthreads();

        // ---- Phase C: z sample + KL
        if (tid < NS) {
            float m = maskf[rb];
            float zp = pmu[tid] + eps_prior[(size_t)rb * NS + tid] * expf(0.5f * plv[tid]);
            float zq = qmu[tid] + eps_post[(size_t)rb * NS + tid] * expf(0.5f * qlv[tid]);
            float z = (m > 0.0f) ? zp : zq;
            zsm[tid] = z;
            z_all[(size_t)rb * NS + tid] = z;
            float vq = fmaxf(expf(qlv[tid]), 1e-5f);
            float vp = fmaxf(expf(plv[tid]), 1e-5f);
            float dm = qmu[tid] - pmu[tid];
            float kle = 0.5f * ((vq + dm * dm) / vp - 1.0f + plv[tid] - qlv[tid]);
            for (int o = 16; o > 0; o >>= 1) kle += __shfl_down(kle, o, 32);
            if (tid == 0) kl_out[rb] = kle;
        }
        __syncthreads();

        // ---- Phase D: gi (tid<64: 96 groups over 64 thr, K=32)
        //               gh (tid>=64: 96g x 2p x 64rows, K=128)
        if (tid < 64) {
            vf4 acc = dotk<4>((const vf4*)gru_wih, 96, tid, 0, zsm);
            gi_s[4 * tid + 0] = acc.x + gru_bih[4 * tid + 0];
            gi_s[4 * tid + 1] = acc.y + gru_bih[4 * tid + 1];
            gi_s[4 * tid + 2] = acc.z + gru_bih[4 * tid + 2];
            gi_s[4 * tid + 3] = acc.w + gru_bih[4 * tid + 3];
            if (tid < 32) {
                int g2 = 64 + tid;
                vf4 a2 = dotk<4>((const vf4*)gru_wih, 96, g2, 0, zsm);
                gi_s[4 * g2 + 0] = a2.x + gru_bih[4 * g2 + 0];
                gi_s[4 * g2 + 1] = a2.y + gru_bih[4 * g2 + 1];
                gi_s[4 * g2 + 2] = a2.z + gru_bih[4 * g2 + 2];
                gi_s[4 * g2 + 3] = a2.w + gru_bih[4 * g2 + 3];
            }
        } else {
            int u = tid - 64;                // 0..191
            int g = u % 96, part = u / 96;   // 96 groups x 2 parts x 64 rows
            vf4 acc = dotk<8>((const vf4*)gru_whh, 96, g, part * 64, deter);
            pbuf4[part * 96 + g] = acc;
        }
        __syncthreads();

        // ---- Phase E: GRU combine + deter update
        if (tid < ND) {
            int j = tid;
            int gr = j >> 2, c = j & 3;
            float hr = gru_bhh[j]          + pbuf[(gr) * 4 + c]            + pbuf[(96 + gr) * 4 + c];
            float hz = gru_bhh[ND + j]     + pbuf[(32 + gr) * 4 + c]       + pbuf[(96 + 32 + gr) * 4 + c];
            float hn = gru_bhh[2 * ND + j] + pbuf[(64 + gr) * 4 + c]       + pbuf[(96 + 64 + gr) * 4 + c];
            float r = sigf(gi_s[j] + hr);
            float u = sigf(gi_s[ND + j] + hz);
            float n = tanhf(gi_s[2 * ND + j] + r * hn);
            float dn = (1.0f - u) * n + u * deter[j];
            deter[j] = dn;
            deter_all[(size_t)rb * ND + j] = dn;
        }
        __syncthreads();
    }
}

// -------- Kernel 4: decoder + recon MSE, 48-way parallel --------
__global__ __launch_bounds__(512) void decoder_kernel(
    const float* __restrict__ deter_all, const float* __restrict__ z_all,
    const float* __restrict__ tgt,
    const float* __restrict__ dec_w1, const float* __restrict__ dec_b1,
    const float* __restrict__ dec_w2, const float* __restrict__ dec_b2,
    float* __restrict__ recon_out)
{
    int rb = blockIdx.x;      // 0..47
    int tid = threadIdx.x;    // 0..511
    __shared__ float din[ND + NS];   // 160
    __shared__ float d1[NH];
    __shared__ float p1[4][NH];
    __shared__ float redb[8];

    if (tid < ND) din[tid] = deter_all[(size_t)rb * ND + tid];
    else if (tid < ND + NS) din[tid] = z_all[(size_t)rb * NS + (tid - ND)];
    __syncthreads();

    {
        int part = tid >> 7, j = tid & 127;
        int k0 = part * 40;
        float a = 0.0f;
        #pragma unroll 8
        for (int k = k0; k < k0 + 40; k++) a += din[k] * dec_w1[k * NH + j];
        p1[part][j] = a;
    }
    __syncthreads();
    if (tid < NH) {
        float a = dec_b1[tid] + p1[0][tid] + p1[1][tid] + p1[2][tid] + p1[3][tid];
        d1[tid] = siluf(a);
    }
    __syncthreads();

    float se = 0.0f;
    const float* trow = tgt + (size_t)rb * NOBS;
    for (int o = tid; o < NOBS; o += 512) {
        float a = dec_b2[o];
        #pragma unroll 8
        for (int i = 0; i < NH; i++) a += d1[i] * dec_w2[i * NOBS + o];
        float df = a - trow[o];
        se += df * df;
    }
    for (int o = 32; o > 0; o >>= 1) se += __shfl_down(se, o);
    if ((tid & 63) == 0) redb[tid >> 6] = se;
    __syncthreads();
    if (tid == 0) {
        float s = 0.0f;
        for (int p = 0; p < 8; p++) s += redb[p];
        recon_out[rb] = s * (1.0f / 768.0f);
    }
}

// -------- Kernel 5: finalize (mask-weighted scalar combine) --------
__global__ void finalize(const float* __restrict__ maskf,
                         const float* __restrict__ recon,
                         const float* __restrict__ kl,
                         float* __restrict__ out)
{
    if (threadIdx.x != 0 || blockIdx.x != 0) return;
    float rl = 0.0f, rs = 0.0f, ka = 0.0f, kn = 0.0f;
    for (int t = 0; t < NV; t++) {
        float ms = 0.0f, rsum = 0.0f, osum = 0.0f, ksum = 0.0f;
        for (int b = 0; b < NB; b++) {
            float m = maskf[t * NB + b];
            ms += m;
            rsum += recon[t * NB + b] * m;
            osum += 1.0f - m;
            ksum += kl[t * NB + b] * (1.0f - m);
        }
        if (ms > 0.0f) { rl += rsum / fmaxf(ms, 1.0f); rs += 1.0f; }
        if (osum > 0.0f) { ka += ksum / fmaxf(osum, 1.0f); kn += 1.0f; }
    }
    out[0] = rl / fmaxf(rs, 1.0f);
    out[1] = (ka / fmaxf(kn, 1.0f)) * 1e-4f;
}

extern "C" void kernel_launch(void* const* d_in, const int* in_sizes, int n_in,
                              void* d_out, int out_size, void* d_ws, size_t ws_size,
                              hipStream_t stream) {
    const float* sf0 = (const float*)d_in[0];
    const float* sf1 = (const float*)d_in[1];
    const float* tf0 = (const float*)d_in[2];
    const float* tf1 = (const float*)d_in[3];
    const void*  cam = d_in[4];
    const float* eps_prior = (const float*)d_in[5];
    const float* eps_post  = (const float*)d_in[6];
    const float* enc_w1 = (const float*)d_in[7];
    const float* enc_b1 = (const float*)d_in[8];
    const float* ln_g   = (const float*)d_in[9];
    const float* ln_b   = (const float*)d_in[10];
    const float* enc_w2 = (const float*)d_in[11];
    const float* enc_b2 = (const float*)d_in[12];
    const float* prior_w1 = (const float*)d_in[13];
    const float* prior_b1 = (const float*)d_in[14];
    const float* prior_w2 = (const float*)d_in[15];
    const float* prior_b2 = (const float*)d_in[16];
    const float* post_w1 = (const float*)d_in[17];
    const float* post_b1 = (const float*)d_in[18];
    const float* post_w2 = (const float*)d_in[19];
    const float* post_b2 = (const float*)d_in[20];
    const float* dec_w1 = (const float*)d_in[21];
    const float* dec_b1 = (const float*)d_in[22];
    const float* dec_w2 = (const float*)d_in[23];
    const float* dec_b2 = (const float*)d_in[24];
    const float* gru_wih = (const float*)d_in[25];
    const float* gru_whh = (const float*)d_in[26];
    const float* gru_bih = (const float*)d_in[27];
    const float* gru_bhh = (const float*)d_in[28];

    float* ws = (float*)d_ws;
    float* obs   = ws;                 // 48*768 = 36864
    float* tgt   = ws + 36864;         // 36864
    float* oe    = ws + 73728;         // 48*128 = 6144
    float* maskf = ws + 79872;         // 48
    float* rec   = ws + 79920;         // 48
    float* klv   = ws + 79968;         // 48
    float* deter_all = ws + 80016;     // 48*128 = 6144
    float* z_all     = ws + 86160;     // 48*32  = 1536
    float* warm_dummy = ws + 87696;    // 64

    // both reductions in one streaming kernel: 2048 blocks x 256 = 8192 waves
    reduce_all<<<RWAVES / 4, 256, 0, stream>>>(sf0, sf1, tf0, tf1, obs, tgt);
    // encoder + mask prep + weight warm
    encoder<<<65, 512, 0, stream>>>(obs, enc_w1, enc_b1, ln_g, ln_b, enc_w2, enc_b2, oe,
                                    cam, maskf,
                                    prior_w1, post_w1, prior_w2, post_w2, gru_wih, gru_whh,
                                    warm_dummy);
    scan_only<<<8, 256, 0, stream>>>(oe, maskf, eps_prior, eps_post,
                                     prior_w1, prior_b1, prior_w2, prior_b2,
                                     post_w1, post_b1, post_w2, post_b2,
                                     gru_wih, gru_whh, gru_bih, gru_bhh,
                                     deter_all, z_all, klv);
    decoder_kernel<<<48, 512, 0, stream>>>(deter_all, z_all, tgt,
                                           dec_w1, dec_b1, dec_w2, dec_b2, rec);
    finalize<<<1, 64, 0, stream>>>(maskf, rec, klv, (float*)d_out);
}

// Round 9
// 127.435 us; speedup vs baseline: 1.4451x; 1.2150x over previous
//
#include <hip/hip_runtime.h>
#include <cstddef>

// Problem constants
constexpr int NB = 8;      // batch
constexpr int NV = 6;      // views (scan length)
constexpr int NS = 32;     // stochastic dim S
constexpr int ND = 128;    // deter dim D
constexpr int NH = 128;    // hidden H
constexpr int NOBS = 768;  // obs dim

// reduction job space: 12288 f0 wave-jobs + 6144 f1 quad-channel wave-jobs per tensor pair
constexpr int NJOBS = 18432;
constexpr int RWAVES = 8192;   // persistent wave count for reductions

typedef float vf4 __attribute__((ext_vector_type(4)));

__device__ __forceinline__ float sigf(float x) { return 1.0f / (1.0f + expf(-x)); }
__device__ __forceinline__ float siluf(float x) { return x / (1.0f + expf(-x)); }

// Defeat LICM/CSE: make the pointer opaque each call so derived loads are not
// provably loop-invariant and cannot be hoisted out of the t-loop.
__device__ __forceinline__ const vf4* lndr(const void* p) {
    asm volatile("" : "+s"(p));
    return (const vf4*)p;
}
// Pin phase boundaries: no compile-time motion of (weight) loads across phases.
#define PHASE_FENCE() do { __builtin_amdgcn_sched_barrier(0); asm volatile("" ::: "memory"); } while (0)

// ---- double-buffered K-dot: NB8 batches of 8 rows, 8 loads always in flight ----
template<int NB8>
__device__ __forceinline__ vf4 dotk(const vf4* __restrict__ w, int ldg, int g, int k0,
                                    const float* __restrict__ x) {
    vf4 acc = {0.f, 0.f, 0.f, 0.f};
    vf4 wa[8], wb[8];
    #pragma unroll
    for (int i = 0; i < 8; i++) wa[i] = w[(size_t)(k0 + i) * ldg + g];
    #pragma unroll
    for (int bb = 0; bb < NB8; bb++) {
        int kb = k0 + bb * 8;
        if ((bb & 1) == 0) {
            if (bb + 1 < NB8) {
                #pragma unroll
                for (int i = 0; i < 8; i++) wb[i] = w[(size_t)(kb + 8 + i) * ldg + g];
            }
            #pragma unroll
            for (int i = 0; i < 8; i++) acc += x[kb + i] * wa[i];
        } else {
            if (bb + 1 < NB8) {
                #pragma unroll
                for (int i = 0; i < 8; i++) wa[i] = w[(size_t)(kb + 8 + i) * ldg + g];
            }
            #pragma unroll
            for (int i = 0; i < 8; i++) acc += x[kb + i] * wb[i];
        }
    }
    return acc;
}

// -------- shared reducer job (nontemporal streaming loads) --------
__device__ __forceinline__ void reduce_job(int wid, int lane,
    const float* __restrict__ f0, const float* __restrict__ f1,
    float* __restrict__ out)
{
    if (wid < 12288) {
        const vf4* s4 = (const vf4*)(f0 + (size_t)wid * 2816);
        vf4 xb[11];
        #pragma unroll
        for (int it = 0; it < 11; it++) xb[it] = __builtin_nontemporal_load(&s4[lane + it * 64]);
        float s = 0.f;
        #pragma unroll
        for (int it = 0; it < 11; it++) s += xb[it].x + xb[it].y + xb[it].z + xb[it].w;
        #pragma unroll
        for (int o = 32; o > 0; o >>= 1) s += __shfl_down(s, o);
        if (lane == 0) {
            int b = wid / 1536, r = wid % 1536, v = r >> 8, c = r & 255;
            out[(size_t)(v * NB + b) * NOBS + c] = s * (1.0f / 2816.0f);
        }
    } else {
        int q = wid - 12288;              // quad index 0..6143
        int g = lane >> 4, sub = lane & 15;
        const vf4* s4 = (const vf4*)(f1 + (size_t)q * 2816);
        vf4 xb[11];
        #pragma unroll
        for (int it = 0; it < 11; it++) xb[it] = __builtin_nontemporal_load(&s4[g * 176 + sub + it * 16]);
        float s = 0.f;
        #pragma unroll
        for (int it = 0; it < 11; it++) s += xb[it].x + xb[it].y + xb[it].z + xb[it].w;
        #pragma unroll
        for (int o = 8; o > 0; o >>= 1) s += __shfl_down(s, o, 16);
        if (sub == 0) {
            int c4 = 4 * q + g;           // f1 channel 0..24575
            int b = c4 / 3072, r = c4 % 3072, v = r >> 9, c = r & 511;
            out[(size_t)(v * NB + b) * NOBS + 256 + c] = s * (1.0f / 704.0f);
        }
    }
}

// -------- Kernel 1: BOTH feature-mean reductions (386 MB, NT streaming) --------
__global__ __launch_bounds__(256) void reduce_all(
    const float* __restrict__ sf0, const float* __restrict__ sf1,
    const float* __restrict__ tf0, const float* __restrict__ tf1,
    float* __restrict__ obs, float* __restrict__ tgt)
{
    int lane = threadIdx.x & 63;
    int w0 = blockIdx.x * 4 + (threadIdx.x >> 6);
    for (int wid = w0; wid < 2 * NJOBS; wid += RWAVES) {
        if (wid < NJOBS) reduce_job(wid, lane, sf0, sf1, obs);
        else             reduce_job(wid - NJOBS, lane, tf0, tf1, tgt);
    }
}

// -------- Kernel 2: encoder (blocks 0-47) + mask prep (block 48) + L3 warm (49-64)
__global__ __launch_bounds__(512) void encoder(
    const float* __restrict__ obs,
    const float* __restrict__ w1, const float* __restrict__ b1,
    const float* __restrict__ g, const float* __restrict__ be,
    const float* __restrict__ w2, const float* __restrict__ b2,
    float* __restrict__ obs_embed,
    const void* cam, float* __restrict__ maskf,
    const float* __restrict__ prior_w1, const float* __restrict__ post_w1,
    const float* __restrict__ prior_w2, const float* __restrict__ post_w2,
    const float* __restrict__ gru_wih,  const float* __restrict__ gru_whh,
    float* __restrict__ warm_dummy)
{
    int tid = threadIdx.x;    // 0..511

    if (blockIdx.x == 48) {
        if (tid != 0) return;
        const int* wi = (const int*)cam;
        bool is_i32 = true;
        for (int i = 0; i < NB * NV; i++) {
            unsigned v = (unsigned)wi[i];
            if (v > 1u) { is_i32 = false; break; }
        }
        const unsigned char* wb = (const unsigned char*)cam;
        for (int b = 0; b < NB; b++)
            for (int v = 0; v < NV; v++) {
                int val = is_i32 ? wi[b * NV + v] : (int)wb[b * NV + v];
                maskf[v * NB + b] = val ? 1.0f : 0.0f;
            }
        return;
    }
    if (blockIdx.x > 48) {
        int wtid = (blockIdx.x - 49) * 512 + tid;    // 0..8191
        const float* arrs[6] = {prior_w1, post_w1, prior_w2, post_w2, gru_wih, gru_whh};
        const int n4s[6] = {4096, 8192, 2048, 2048, 3072, 12288};  // float4 counts
        float s = 0.f;
        for (int a = 0; a < 6; a++) {
            const vf4* p = (const vf4*)arrs[a];
            int n4 = n4s[a];
            for (int i = wtid; i < n4; i += 16 * 512) {
                vf4 x = p[i];
                s += x.x + x.y + x.z + x.w;
            }
        }
        warm_dummy[wtid & 63] = s;
        return;
    }

    __shared__ float xs[NOBS];
    __shared__ float hs[NH];
    __shared__ float pE[4][NH];
    __shared__ float red[2], red2[2];
    int r = blockIdx.x;       // r = v*NB + b
    const float* row = obs + (size_t)r * NOBS;
    for (int i = tid; i < NOBS; i += 512) xs[i] = row[i];
    __syncthreads();

    {
        int part = tid >> 7, j = tid & 127;
        int k0 = part * 192;
        float a = 0.0f;
        #pragma unroll 8
        for (int k = k0; k < k0 + 192; k++) a += xs[k] * w1[k * NH + j];
        pE[part][j] = a;
    }
    __syncthreads();

    float a1 = 0.0f;
    if (tid < NH) {
        a1 = b1[tid] + pE[0][tid] + pE[1][tid] + pE[2][tid] + pE[3][tid];
        float v = a1;
        for (int o = 32; o > 0; o >>= 1) v += __shfl_down(v, o);
        if ((tid & 63) == 0) red[tid >> 6] = v;
    }
    __syncthreads();
    if (tid < NH) {
        float mu = (red[0] + red[1]) * (1.0f / 128.0f);
        float d = a1 - mu;
        float dv = d * d;
        for (int o = 32; o > 0; o >>= 1) dv += __shfl_down(dv, o);
        if ((tid & 63) == 0) red2[tid >> 6] = dv;
    }
    __syncthreads();
    if (tid < NH) {
        float mu = (red[0] + red[1]) * (1.0f / 128.0f);
        float var = (red2[0] + red2[1]) * (1.0f / 128.0f);
        float xn = (a1 - mu) * rsqrtf(var + 1e-5f) * g[tid] + be[tid];
        hs[tid] = siluf(xn);
    }
    __syncthreads();

    {
        int part = tid >> 7, j = tid & 127;
        int k0 = part * 32;
        float a = 0.0f;
        #pragma unroll 8
        for (int k = k0; k < k0 + 32; k++) a += hs[k] * w2[k * NH + j];
        pE[part][j] = a;
    }
    __syncthreads();
    if (tid < NH) {
        float a = b2[tid] + pE[0][tid] + pE[1][tid] + pE[2][tid] + pE[3][tid];
        obs_embed[(size_t)r * NH + tid] = siluf(a);
    }
}

// -------- Kernel 3: RSSM scan, 256 thr, phase-fenced + laundered pointers --------
__global__ __launch_bounds__(256) void scan_only(
    const float* __restrict__ obs_embed,
    const float* __restrict__ maskf,
    const float* __restrict__ eps_prior, const float* __restrict__ eps_post,
    const float* __restrict__ prior_w1, const float* __restrict__ prior_b1,
    const float* __restrict__ prior_w2, const float* __restrict__ prior_b2,
    const float* __restrict__ post_w1, const float* __restrict__ post_b1,
    const float* __restrict__ post_w2, const float* __restrict__ post_b2,
    const float* __restrict__ gru_wih, const float* __restrict__ gru_whh,
    const float* __restrict__ gru_bih, const float* __restrict__ gru_bhh,
    float* __restrict__ deter_all, float* __restrict__ z_all,
    float* __restrict__ kl_out)
{
    __shared__ float pbuf[1024];         // 256 float4 split-K partials
    __shared__ float gi_s[3 * ND];
    __shared__ float deter_obs[ND + NH]; // deter [0,128), obs_e [128,256)
    __shared__ float t12[2 * NH];        // t1 [0,128), t2 [128,256)
    __shared__ float pmu[NS], plv[NS], qmu[NS], qlv[NS], zsm[NS];
    vf4* pbuf4 = (vf4*)pbuf;
    float* deter = deter_obs;

    int b = blockIdx.x;       // 0..7
    int tid = threadIdx.x;    // 0..255

    if (tid < ND) deter[tid] = 0.0f;
    __syncthreads();

    for (int t = 0; t < NV; t++) {
        // opaque per-iteration weight pointers: nothing below is loop-invariant
        const vf4* w_pw1  = lndr(prior_w1);
        const vf4* w_ow1  = lndr(post_w1);
        const vf4* w_pw2  = lndr(prior_w2);
        const vf4* w_ow2  = lndr(post_w2);
        const vf4* w_gih  = lndr(gru_wih);
        const vf4* w_ghh  = lndr(gru_whh);

        int rb = t * NB + b;
        if (tid < NH) deter_obs[ND + tid] = obs_embed[(size_t)rb * NH + tid];
        __syncthreads();
        PHASE_FENCE();

        // ---- Phase A: prior hidden (tid<128: 32g x 4p x 32rows, K=128)
        //               post hidden  (tid>=128: 32g x 4p x 64rows, K=256)
        if (tid < 128) {
            int g = tid & 31, part = tid >> 5;
            vf4 acc = dotk<4>(w_pw1, 32, g, part * 32, deter);
            pbuf4[part * 32 + g] = acc;
        } else {
            int u = tid - 128;
            int g = u & 31, part = u >> 5;
            vf4 acc = dotk<8>(w_ow1, 32, g, part * 64, deter_obs);
            pbuf4[128 + part * 32 + g] = acc;
        }
        __syncthreads();
        PHASE_FENCE();
        {
            int j = tid;
            float a = 0.0f;
            if (j < NH) {
                int g = j >> 2, c = j & 3;
                #pragma unroll
                for (int p = 0; p < 4; p++) a += pbuf[(p * 32 + g) * 4 + c];
                t12[j] = siluf(a + prior_b1[j]);
            } else {
                int jj = j - NH;
                int g = jj >> 2, c = jj & 3;
                #pragma unroll
                for (int p = 0; p < 4; p++) a += pbuf[(128 + p * 32 + g) * 4 + c];
                t12[NH + jj] = siluf(a + post_b1[jj]);
            }
        }
        __syncthreads();
        PHASE_FENCE();

        // ---- Phase B: prior2 (tid<128) | post2 (tid>=128), 16g x 8p x 16rows, K=128
        {
            bool isPrior = tid < 128;
            int u = isPrior ? tid : tid - 128;
            int g = u & 15, part = u >> 4;
            const vf4* w = isPrior ? w_pw2 : w_ow2;     // [128][16 f4]
            const float* act = t12 + (isPrior ? 0 : NH);
            vf4 acc = dotk<2>(w, 16, g, part * 16, act);
            pbuf4[(isPrior ? 0 : 128) + part * 16 + g] = acc;
        }
        __syncthreads();
        PHASE_FENCE();
        if (tid < 128) {
            int j = tid;
            float a = 0.0f;
            if (j < 64) {
                int g = j >> 2, c = j & 3;
                #pragma unroll
                for (int p = 0; p < 8; p++) a += pbuf[(p * 16 + g) * 4 + c];
                a += prior_b2[j];
                if (j < NS) pmu[j] = a; else plv[j - NS] = a;
            } else {
                int jj = j - 64;
                int g = jj >> 2, c = jj & 3;
                #pragma unroll
                for (int p = 0; p < 8; p++) a += pbuf[(128 + p * 16 + g) * 4 + c];
                a += post_b2[jj];
                if (jj < NS) qmu[jj] = a; else qlv[jj - NS] = a;
            }
        }
        __syncthreads();
        PHASE_FENCE();

        // ---- Phase C: z sample + KL
        if (tid < NS) {
            float m = maskf[rb];
            float zp = pmu[tid] + eps_prior[(size_t)rb * NS + tid] * expf(0.5f * plv[tid]);
            float zq = qmu[tid] + eps_post[(size_t)rb * NS + tid] * expf(0.5f * qlv[tid]);
            float z = (m > 0.0f) ? zp : zq;
            zsm[tid] = z;
            z_all[(size_t)rb * NS + tid] = z;
            float vq = fmaxf(expf(qlv[tid]), 1e-5f);
            float vp = fmaxf(expf(plv[tid]), 1e-5f);
            float dm = qmu[tid] - pmu[tid];
            float kle = 0.5f * ((vq + dm * dm) / vp - 1.0f + plv[tid] - qlv[tid]);
            for (int o = 16; o > 0; o >>= 1) kle += __shfl_down(kle, o, 32);
            if (tid == 0) kl_out[rb] = kle;
        }
        __syncthreads();
        PHASE_FENCE();

        // ---- Phase D: gi (tid<64, K=32) + gh (tid>=64: 96g x 2p x 64rows, K=128)
        if (tid < 64) {
            vf4 acc = dotk<4>(w_gih, 96, tid, 0, zsm);
            gi_s[4 * tid + 0] = acc.x + gru_bih[4 * tid + 0];
            gi_s[4 * tid + 1] = acc.y + gru_bih[4 * tid + 1];
            gi_s[4 * tid + 2] = acc.z + gru_bih[4 * tid + 2];
            gi_s[4 * tid + 3] = acc.w + gru_bih[4 * tid + 3];
            if (tid < 32) {
                int g2 = 64 + tid;
                vf4 a2 = dotk<4>(w_gih, 96, g2, 0, zsm);
                gi_s[4 * g2 + 0] = a2.x + gru_bih[4 * g2 + 0];
                gi_s[4 * g2 + 1] = a2.y + gru_bih[4 * g2 + 1];
                gi_s[4 * g2 + 2] = a2.z + gru_bih[4 * g2 + 2];
                gi_s[4 * g2 + 3] = a2.w + gru_bih[4 * g2 + 3];
            }
        } else {
            int u = tid - 64;                // 0..191
            int g = u % 96, part = u / 96;   // 96 groups x 2 parts x 64 rows
            vf4 acc = dotk<8>(w_ghh, 96, g, part * 64, deter);
            pbuf4[part * 96 + g] = acc;
        }
        __syncthreads();
        PHASE_FENCE();

        // ---- Phase E: GRU combine + deter update
        if (tid < ND) {
            int j = tid;
            int gr = j >> 2, c = j & 3;
            float hr = gru_bhh[j]          + pbuf[(gr) * 4 + c]      + pbuf[(96 + gr) * 4 + c];
            float hz = gru_bhh[ND + j]     + pbuf[(32 + gr) * 4 + c] + pbuf[(96 + 32 + gr) * 4 + c];
            float hn = gru_bhh[2 * ND + j] + pbuf[(64 + gr) * 4 + c] + pbuf[(96 + 64 + gr) * 4 + c];
            float r = sigf(gi_s[j] + hr);
            float u = sigf(gi_s[ND + j] + hz);
            float n = tanhf(gi_s[2 * ND + j] + r * hn);
            float dn = (1.0f - u) * n + u * deter[j];
            deter[j] = dn;
            deter_all[(size_t)rb * ND + j] = dn;
        }
        __syncthreads();
        PHASE_FENCE();
    }
}

// -------- Kernel 4: decoder + recon MSE, 48-way parallel --------
__global__ __launch_bounds__(512) void decoder_kernel(
    const float* __restrict__ deter_all, const float* __restrict__ z_all,
    const float* __restrict__ tgt,
    const float* __restrict__ dec_w1, const float* __restrict__ dec_b1,
    const float* __restrict__ dec_w2, const float* __restrict__ dec_b2,
    float* __restrict__ recon_out)
{
    int rb = blockIdx.x;      // 0..47
    int tid = threadIdx.x;    // 0..511
    __shared__ float din[ND + NS];   // 160
    __shared__ float d1[NH];
    __shared__ float p1[4][NH];
    __shared__ float redb[8];

    if (tid < ND) din[tid] = deter_all[(size_t)rb * ND + tid];
    else if (tid < ND + NS) din[tid] = z_all[(size_t)rb * NS + (tid - ND)];
    __syncthreads();

    {
        int part = tid >> 7, j = tid & 127;
        int k0 = part * 40;
        float a = 0.0f;
        #pragma unroll 8
        for (int k = k0; k < k0 + 40; k++) a += din[k] * dec_w1[k * NH + j];
        p1[part][j] = a;
    }
    __syncthreads();
    if (tid < NH) {
        float a = dec_b1[tid] + p1[0][tid] + p1[1][tid] + p1[2][tid] + p1[3][tid];
        d1[tid] = siluf(a);
    }
    __syncthreads();

    float se = 0.0f;
    const float* trow = tgt + (size_t)rb * NOBS;
    for (int o = tid; o < NOBS; o += 512) {
        float a = dec_b2[o];
        #pragma unroll 8
        for (int i = 0; i < NH; i++) a += d1[i] * dec_w2[i * NOBS + o];
        float df = a - trow[o];
        se += df * df;
    }
    for (int o = 32; o > 0; o >>= 1) se += __shfl_down(se, o);
    if ((tid & 63) == 0) redb[tid >> 6] = se;
    __syncthreads();
    if (tid == 0) {
        float s = 0.0f;
        for (int p = 0; p < 8; p++) s += redb[p];
        recon_out[rb] = s * (1.0f / 768.0f);
    }
}

// -------- Kernel 5: finalize (mask-weighted scalar combine) --------
__global__ void finalize(const float* __restrict__ maskf,
                         const float* __restrict__ recon,
                         const float* __restrict__ kl,
                         float* __restrict__ out)
{
    if (threadIdx.x != 0 || blockIdx.x != 0) return;
    float rl = 0.0f, rs = 0.0f, ka = 0.0f, kn = 0.0f;
    for (int t = 0; t < NV; t++) {
        float ms = 0.0f, rsum = 0.0f, osum = 0.0f, ksum = 0.0f;
        for (int b = 0; b < NB; b++) {
            float m = maskf[t * NB + b];
            ms += m;
            rsum += recon[t * NB + b] * m;
            osum += 1.0f - m;
            ksum += kl[t * NB + b] * (1.0f - m);
        }
        if (ms > 0.0f) { rl += rsum / fmaxf(ms, 1.0f); rs += 1.0f; }
        if (osum > 0.0f) { ka += ksum / fmaxf(osum, 1.0f); kn += 1.0f; }
    }
    out[0] = rl / fmaxf(rs, 1.0f);
    out[1] = (ka / fmaxf(kn, 1.0f)) * 1e-4f;
}

extern "C" void kernel_launch(void* const* d_in, const int* in_sizes, int n_in,
                              void* d_out, int out_size, void* d_ws, size_t ws_size,
                              hipStream_t stream) {
    const float* sf0 = (const float*)d_in[0];
    const float* sf1 = (const float*)d_in[1];
    const float* tf0 = (const float*)d_in[2];
    const float* tf1 = (const float*)d_in[3];
    const void*  cam = d_in[4];
    const float* eps_prior = (const float*)d_in[5];
    const float* eps_post  = (const float*)d_in[6];
    const float* enc_w1 = (const float*)d_in[7];
    const float* enc_b1 = (const float*)d_in[8];
    const float* ln_g   = (const float*)d_in[9];
    const float* ln_b   = (const float*)d_in[10];
    const float* enc_w2 = (const float*)d_in[11];
    const float* enc_b2 = (const float*)d_in[12];
    const float* prior_w1 = (const float*)d_in[13];
    const float* prior_b1 = (const float*)d_in[14];
    const float* prior_w2 = (const float*)d_in[15];
    const float* prior_b2 = (const float*)d_in[16];
    const float* post_w1 = (const float*)d_in[17];
    const float* post_b1 = (const float*)d_in[18];
    const float* post_w2 = (const float*)d_in[19];
    const float* post_b2 = (const float*)d_in[20];
    const float* dec_w1 = (const float*)d_in[21];
    const float* dec_b1 = (const float*)d_in[22];
    const float* dec_w2 = (const float*)d_in[23];
    const float* dec_b2 = (const float*)d_in[24];
    const float* gru_wih = (const float*)d_in[25];
    const float* gru_whh = (const float*)d_in[26];
    const float* gru_bih = (const float*)d_in[27];
    const float* gru_bhh = (const float*)d_in[28];

    float* ws = (float*)d_ws;
    float* obs   = ws;                 // 48*768 = 36864
    float* tgt   = ws + 36864;         // 36864
    float* oe    = ws + 73728;         // 48*128 = 6144
    float* maskf = ws + 79872;         // 48
    float* rec   = ws + 79920;         // 48
    float* klv   = ws + 79968;         // 48
    float* deter_all = ws + 80016;     // 48*128 = 6144
    float* z_all     = ws + 86160;     // 48*32  = 1536
    float* warm_dummy = ws + 87696;    // 64

    // both reductions in one streaming kernel: 2048 blocks x 256 = 8192 waves
    reduce_all<<<RWAVES / 4, 256, 0, stream>>>(sf0, sf1, tf0, tf1, obs, tgt);
    // encoder + mask prep + weight warm
    encoder<<<65, 512, 0, stream>>>(obs, enc_w1, enc_b1, ln_g, ln_b, enc_w2, enc_b2, oe,
                                    cam, maskf,
                                    prior_w1, post_w1, prior_w2, post_w2, gru_wih, gru_whh,
                                    warm_dummy);
    scan_only<<<8, 256, 0, stream>>>(oe, maskf, eps_prior, eps_post,
                                     prior_w1, prior_b1, prior_w2, prior_b2,
                                     post_w1, post_b1, post_w2, post_b2,
                                     gru_wih, gru_whh, gru_bih, gru_bhh,
                                     deter_all, z_all, klv);
    decoder_kernel<<<48, 512, 0, stream>>>(deter_all, z_all, tgt,
                                           dec_w1, dec_b1, dec_w2, dec_b2, rec);
    finalize<<<1, 64, 0, stream>>>(maskf, rec, klv, (float*)d_out);
}

// Round 10
// 98.289 us; speedup vs baseline: 1.8737x; 1.2965x over previous
//
#include <hip/hip_runtime.h>
#include <cstddef>

// Problem constants
constexpr int NB = 8;      // batch
constexpr int NV = 6;      // views (scan length)
constexpr int NS = 32;     // stochastic dim S
constexpr int ND = 128;    // deter dim D
constexpr int NH = 128;    // hidden H
constexpr int NOBS = 768;  // obs dim

// reduction job space: 12288 f0 wave-jobs + 6144 f1 quad-channel wave-jobs per tensor pair
constexpr int NJOBS = 18432;
constexpr int RWAVES = 8192;   // persistent wave count for reductions

typedef float vf4 __attribute__((ext_vector_type(4)));

__device__ __forceinline__ float sigf(float x) { return 1.0f / (1.0f + expf(-x)); }
__device__ __forceinline__ float siluf(float x) { return x / (1.0f + expf(-x)); }

// Defeat LICM/CSE: make the pointer opaque each call so derived loads are not
// provably loop-invariant and cannot be hoisted out of the t-loop.
__device__ __forceinline__ const vf4* lndr(const void* p) {
    asm volatile("" : "+s"(p));
    return (const vf4*)p;
}
// Pin phase boundaries: no compile-time motion of (weight) loads across phases.
#define PHASE_FENCE() do { __builtin_amdgcn_sched_barrier(0); asm volatile("" ::: "memory"); } while (0)

// ---- double-buffered K-dot: NB8 batches of 8 rows, 8 loads always in flight ----
template<int NB8>
__device__ __forceinline__ vf4 dotk(const vf4* __restrict__ w, int ldg, int g, int k0,
                                    const float* __restrict__ x) {
    vf4 acc = {0.f, 0.f, 0.f, 0.f};
    vf4 wa[8], wb[8];
    #pragma unroll
    for (int i = 0; i < 8; i++) wa[i] = w[(size_t)(k0 + i) * ldg + g];
    #pragma unroll
    for (int bb = 0; bb < NB8; bb++) {
        int kb = k0 + bb * 8;
        if ((bb & 1) == 0) {
            if (bb + 1 < NB8) {
                #pragma unroll
                for (int i = 0; i < 8; i++) wb[i] = w[(size_t)(kb + 8 + i) * ldg + g];
            }
            #pragma unroll
            for (int i = 0; i < 8; i++) acc += x[kb + i] * wa[i];
        } else {
            if (bb + 1 < NB8) {
                #pragma unroll
                for (int i = 0; i < 8; i++) wa[i] = w[(size_t)(kb + 8 + i) * ldg + g];
            }
            #pragma unroll
            for (int i = 0; i < 8; i++) acc += x[kb + i] * wb[i];
        }
    }
    return acc;
}

// -------- shared reducer job (nontemporal streaming loads) --------
__device__ __forceinline__ void reduce_job(int wid, int lane,
    const float* __restrict__ f0, const float* __restrict__ f1,
    float* __restrict__ out)
{
    if (wid < 12288) {
        const vf4* s4 = (const vf4*)(f0 + (size_t)wid * 2816);
        vf4 xb[11];
        #pragma unroll
        for (int it = 0; it < 11; it++) xb[it] = __builtin_nontemporal_load(&s4[lane + it * 64]);
        float s = 0.f;
        #pragma unroll
        for (int it = 0; it < 11; it++) s += xb[it].x + xb[it].y + xb[it].z + xb[it].w;
        #pragma unroll
        for (int o = 32; o > 0; o >>= 1) s += __shfl_down(s, o);
        if (lane == 0) {
            int b = wid / 1536, r = wid % 1536, v = r >> 8, c = r & 255;
            out[(size_t)(v * NB + b) * NOBS + c] = s * (1.0f / 2816.0f);
        }
    } else {
        int q = wid - 12288;              // quad index 0..6143
        int g = lane >> 4, sub = lane & 15;
        const vf4* s4 = (const vf4*)(f1 + (size_t)q * 2816);
        vf4 xb[11];
        #pragma unroll
        for (int it = 0; it < 11; it++) xb[it] = __builtin_nontemporal_load(&s4[g * 176 + sub + it * 16]);
        float s = 0.f;
        #pragma unroll
        for (int it = 0; it < 11; it++) s += xb[it].x + xb[it].y + xb[it].z + xb[it].w;
        #pragma unroll
        for (int o = 8; o > 0; o >>= 1) s += __shfl_down(s, o, 16);
        if (sub == 0) {
            int c4 = 4 * q + g;           // f1 channel 0..24575
            int b = c4 / 3072, r = c4 % 3072, v = r >> 9, c = r & 511;
            out[(size_t)(v * NB + b) * NOBS + 256 + c] = s * (1.0f / 704.0f);
        }
    }
}

// -------- Kernel 1: student feature means (193 MB, NT streaming) --------
__global__ __launch_bounds__(256) void reduce_obs(
    const float* __restrict__ sf0, const float* __restrict__ sf1,
    float* __restrict__ obs)
{
    int lane = threadIdx.x & 63;
    int w0 = blockIdx.x * 4 + (threadIdx.x >> 6);
    for (int wid = w0; wid < NJOBS; wid += RWAVES)
        reduce_job(wid, lane, sf0, sf1, obs);
}

// -------- Kernel 2: encoder (blocks 0-47) + mask prep (block 48) + L3 warm (49-64)
__global__ __launch_bounds__(512) void encoder(
    const float* __restrict__ obs,
    const float* __restrict__ w1, const float* __restrict__ b1,
    const float* __restrict__ g, const float* __restrict__ be,
    const float* __restrict__ w2, const float* __restrict__ b2,
    float* __restrict__ obs_embed,
    const void* cam, float* __restrict__ maskf,
    const float* __restrict__ prior_w1, const float* __restrict__ post_w1,
    const float* __restrict__ prior_w2, const float* __restrict__ post_w2,
    const float* __restrict__ gru_wih,  const float* __restrict__ gru_whh,
    float* __restrict__ warm_dummy)
{
    int tid = threadIdx.x;    // 0..511

    if (blockIdx.x == 48) {
        if (tid != 0) return;
        const int* wi = (const int*)cam;
        bool is_i32 = true;
        for (int i = 0; i < NB * NV; i++) {
            unsigned v = (unsigned)wi[i];
            if (v > 1u) { is_i32 = false; break; }
        }
        const unsigned char* wb = (const unsigned char*)cam;
        for (int b = 0; b < NB; b++)
            for (int v = 0; v < NV; v++) {
                int val = is_i32 ? wi[b * NV + v] : (int)wb[b * NV + v];
                maskf[v * NB + b] = val ? 1.0f : 0.0f;
            }
        return;
    }
    if (blockIdx.x > 48) {
        int wtid = (blockIdx.x - 49) * 512 + tid;    // 0..8191
        const float* arrs[6] = {prior_w1, post_w1, prior_w2, post_w2, gru_wih, gru_whh};
        const int n4s[6] = {4096, 8192, 2048, 2048, 3072, 12288};  // float4 counts
        float s = 0.f;
        for (int a = 0; a < 6; a++) {
            const vf4* p = (const vf4*)arrs[a];
            int n4 = n4s[a];
            for (int i = wtid; i < n4; i += 16 * 512) {
                vf4 x = p[i];
                s += x.x + x.y + x.z + x.w;
            }
        }
        warm_dummy[wtid & 63] = s;
        return;
    }

    __shared__ float xs[NOBS];
    __shared__ float hs[NH];
    __shared__ float pE[4][NH];
    __shared__ float red[2], red2[2];
    int r = blockIdx.x;       // r = v*NB + b
    const float* row = obs + (size_t)r * NOBS;
    for (int i = tid; i < NOBS; i += 512) xs[i] = row[i];
    __syncthreads();

    {
        int part = tid >> 7, j = tid & 127;
        int k0 = part * 192;
        float a = 0.0f;
        #pragma unroll 8
        for (int k = k0; k < k0 + 192; k++) a += xs[k] * w1[k * NH + j];
        pE[part][j] = a;
    }
    __syncthreads();

    float a1 = 0.0f;
    if (tid < NH) {
        a1 = b1[tid] + pE[0][tid] + pE[1][tid] + pE[2][tid] + pE[3][tid];
        float v = a1;
        for (int o = 32; o > 0; o >>= 1) v += __shfl_down(v, o);
        if ((tid & 63) == 0) red[tid >> 6] = v;
    }
    __syncthreads();
    if (tid < NH) {
        float mu = (red[0] + red[1]) * (1.0f / 128.0f);
        float d = a1 - mu;
        float dv = d * d;
        for (int o = 32; o > 0; o >>= 1) dv += __shfl_down(dv, o);
        if ((tid & 63) == 0) red2[tid >> 6] = dv;
    }
    __syncthreads();
    if (tid < NH) {
        float mu = (red[0] + red[1]) * (1.0f / 128.0f);
        float var = (red2[0] + red2[1]) * (1.0f / 128.0f);
        float xn = (a1 - mu) * rsqrtf(var + 1e-5f) * g[tid] + be[tid];
        hs[tid] = siluf(xn);
    }
    __syncthreads();

    {
        int part = tid >> 7, j = tid & 127;
        int k0 = part * 32;
        float a = 0.0f;
        #pragma unroll 8
        for (int k = k0; k < k0 + 32; k++) a += hs[k] * w2[k * NH + j];
        pE[part][j] = a;
    }
    __syncthreads();
    if (tid < NH) {
        float a = b2[tid] + pE[0][tid] + pE[1][tid] + pE[2][tid] + pE[3][tid];
        obs_embed[(size_t)r * NH + tid] = siluf(a);
    }
}

// -------- Kernel 3: fused — scan (blocks 0-7, r9 spill-free version) +
//                    teacher NT reduce (blocks 8+, doesn't allocate in cache) --------
__global__ __launch_bounds__(256) void fused_scan_tgt(
    const float* __restrict__ obs_embed,
    const float* __restrict__ maskf,
    const float* __restrict__ eps_prior, const float* __restrict__ eps_post,
    const float* __restrict__ prior_w1, const float* __restrict__ prior_b1,
    const float* __restrict__ prior_w2, const float* __restrict__ prior_b2,
    const float* __restrict__ post_w1, const float* __restrict__ post_b1,
    const float* __restrict__ post_w2, const float* __restrict__ post_b2,
    const float* __restrict__ gru_wih, const float* __restrict__ gru_whh,
    const float* __restrict__ gru_bih, const float* __restrict__ gru_bhh,
    float* __restrict__ deter_all, float* __restrict__ z_all,
    float* __restrict__ kl_out,
    const float* __restrict__ tf0, const float* __restrict__ tf1,
    float* __restrict__ tgt)
{
    __shared__ float pbuf[1024];         // 256 float4 split-K partials
    __shared__ float gi_s[3 * ND];
    __shared__ float deter_obs[ND + NH]; // deter [0,128), obs_e [128,256)
    __shared__ float t12[2 * NH];        // t1 [0,128), t2 [128,256)
    __shared__ float pmu[NS], plv[NS], qmu[NS], qlv[NS], zsm[NS];
    vf4* pbuf4 = (vf4*)pbuf;
    float* deter = deter_obs;

    int tid = threadIdx.x;    // 0..255

    if (blockIdx.x >= 8) {
        // ---- teacher-feature NT reduction (concurrent with the scan)
        int lane = tid & 63;
        int w0 = (blockIdx.x - 8) * 4 + (tid >> 6);
        for (int wid = w0; wid < NJOBS; wid += RWAVES)
            reduce_job(wid, lane, tf0, tf1, tgt);
        return;
    }

    int b = blockIdx.x;       // 0..7

    if (tid < ND) deter[tid] = 0.0f;
    __syncthreads();

    for (int t = 0; t < NV; t++) {
        // opaque per-iteration weight pointers: nothing below is loop-invariant
        const vf4* w_pw1  = lndr(prior_w1);
        const vf4* w_ow1  = lndr(post_w1);
        const vf4* w_pw2  = lndr(prior_w2);
        const vf4* w_ow2  = lndr(post_w2);
        const vf4* w_gih  = lndr(gru_wih);
        const vf4* w_ghh  = lndr(gru_whh);

        int rb = t * NB + b;
        if (tid < NH) deter_obs[ND + tid] = obs_embed[(size_t)rb * NH + tid];
        __syncthreads();
        PHASE_FENCE();

        // ---- Phase A: prior hidden (tid<128: 32g x 4p x 32rows, K=128)
        //               post hidden  (tid>=128: 32g x 4p x 64rows, K=256)
        if (tid < 128) {
            int g = tid & 31, part = tid >> 5;
            vf4 acc = dotk<4>(w_pw1, 32, g, part * 32, deter);
            pbuf4[part * 32 + g] = acc;
        } else {
            int u = tid - 128;
            int g = u & 31, part = u >> 5;
            vf4 acc = dotk<8>(w_ow1, 32, g, part * 64, deter_obs);
            pbuf4[128 + part * 32 + g] = acc;
        }
        __syncthreads();
        PHASE_FENCE();
        {
            int j = tid;
            float a = 0.0f;
            if (j < NH) {
                int g = j >> 2, c = j & 3;
                #pragma unroll
                for (int p = 0; p < 4; p++) a += pbuf[(p * 32 + g) * 4 + c];
                t12[j] = siluf(a + prior_b1[j]);
            } else {
                int jj = j - NH;
                int g = jj >> 2, c = jj & 3;
                #pragma unroll
                for (int p = 0; p < 4; p++) a += pbuf[(128 + p * 32 + g) * 4 + c];
                t12[NH + jj] = siluf(a + post_b1[jj]);
            }
        }
        __syncthreads();
        PHASE_FENCE();

        // ---- Phase B: prior2 (tid<128) | post2 (tid>=128), 16g x 8p x 16rows, K=128
        {
            bool isPrior = tid < 128;
            int u = isPrior ? tid : tid - 128;
            int g = u & 15, part = u >> 4;
            const vf4* w = isPrior ? w_pw2 : w_ow2;     // [128][16 f4]
            const float* act = t12 + (isPrior ? 0 : NH);
            vf4 acc = dotk<2>(w, 16, g, part * 16, act);
            pbuf4[(isPrior ? 0 : 128) + part * 16 + g] = acc;
        }
        __syncthreads();
        PHASE_FENCE();
        if (tid < 128) {
            int j = tid;
            float a = 0.0f;
            if (j < 64) {
                int g = j >> 2, c = j & 3;
                #pragma unroll
                for (int p = 0; p < 8; p++) a += pbuf[(p * 16 + g) * 4 + c];
                a += prior_b2[j];
                if (j < NS) pmu[j] = a; else plv[j - NS] = a;
            } else {
                int jj = j - 64;
                int g = jj >> 2, c = jj & 3;
                #pragma unroll
                for (int p = 0; p < 8; p++) a += pbuf[(128 + p * 16 + g) * 4 + c];
                a += post_b2[jj];
                if (jj < NS) qmu[jj] = a; else qlv[jj - NS] = a;
            }
        }
        __syncthreads();
        PHASE_FENCE();

        // ---- Phase C: z sample + KL
        if (tid < NS) {
            float m = maskf[rb];
            float zp = pmu[tid] + eps_prior[(size_t)rb * NS + tid] * expf(0.5f * plv[tid]);
            float zq = qmu[tid] + eps_post[(size_t)rb * NS + tid] * expf(0.5f * qlv[tid]);
            float z = (m > 0.0f) ? zp : zq;
            zsm[tid] = z;
            z_all[(size_t)rb * NS + tid] = z;
            float vq = fmaxf(expf(qlv[tid]), 1e-5f);
            float vp = fmaxf(expf(plv[tid]), 1e-5f);
            float dm = qmu[tid] - pmu[tid];
            float kle = 0.5f * ((vq + dm * dm) / vp - 1.0f + plv[tid] - qlv[tid]);
            for (int o = 16; o > 0; o >>= 1) kle += __shfl_down(kle, o, 32);
            if (tid == 0) kl_out[rb] = kle;
        }
        __syncthreads();
        PHASE_FENCE();

        // ---- Phase D: gi (tid<64, K=32) + gh (tid>=64: 96g x 2p x 64rows, K=128)
        if (tid < 64) {
            vf4 acc = dotk<4>(w_gih, 96, tid, 0, zsm);
            gi_s[4 * tid + 0] = acc.x + gru_bih[4 * tid + 0];
            gi_s[4 * tid + 1] = acc.y + gru_bih[4 * tid + 1];
            gi_s[4 * tid + 2] = acc.z + gru_bih[4 * tid + 2];
            gi_s[4 * tid + 3] = acc.w + gru_bih[4 * tid + 3];
            if (tid < 32) {
                int g2 = 64 + tid;
                vf4 a2 = dotk<4>(w_gih, 96, g2, 0, zsm);
                gi_s[4 * g2 + 0] = a2.x + gru_bih[4 * g2 + 0];
                gi_s[4 * g2 + 1] = a2.y + gru_bih[4 * g2 + 1];
                gi_s[4 * g2 + 2] = a2.z + gru_bih[4 * g2 + 2];
                gi_s[4 * g2 + 3] = a2.w + gru_bih[4 * g2 + 3];
            }
        } else {
            int u = tid - 64;                // 0..191
            int g = u % 96, part = u / 96;   // 96 groups x 2 parts x 64 rows
            vf4 acc = dotk<8>(w_ghh, 96, g, part * 64, deter);
            pbuf4[part * 96 + g] = acc;
        }
        __syncthreads();
        PHASE_FENCE();

        // ---- Phase E: GRU combine + deter update
        if (tid < ND) {
            int j = tid;
            int gr = j >> 2, c = j & 3;
            float hr = gru_bhh[j]          + pbuf[(gr) * 4 + c]      + pbuf[(96 + gr) * 4 + c];
            float hz = gru_bhh[ND + j]     + pbuf[(32 + gr) * 4 + c] + pbuf[(96 + 32 + gr) * 4 + c];
            float hn = gru_bhh[2 * ND + j] + pbuf[(64 + gr) * 4 + c] + pbuf[(96 + 64 + gr) * 4 + c];
            float r = sigf(gi_s[j] + hr);
            float u = sigf(gi_s[ND + j] + hz);
            float n = tanhf(gi_s[2 * ND + j] + r * hn);
            float dn = (1.0f - u) * n + u * deter[j];
            deter[j] = dn;
            deter_all[(size_t)rb * ND + j] = dn;
        }
        __syncthreads();
        PHASE_FENCE();
    }
}

// -------- Kernel 4: decoder + recon MSE, 48-way parallel --------
__global__ __launch_bounds__(512) void decoder_kernel(
    const float* __restrict__ deter_all, const float* __restrict__ z_all,
    const float* __restrict__ tgt,
    const float* __restrict__ dec_w1, const float* __restrict__ dec_b1,
    const float* __restrict__ dec_w2, const float* __restrict__ dec_b2,
    float* __restrict__ recon_out)
{
    int rb = blockIdx.x;      // 0..47
    int tid = threadIdx.x;    // 0..511
    __shared__ float din[ND + NS];   // 160
    __shared__ float d1[NH];
    __shared__ float p1[4][NH];
    __shared__ float redb[8];

    if (tid < ND) din[tid] = deter_all[(size_t)rb * ND + tid];
    else if (tid < ND + NS) din[tid] = z_all[(size_t)rb * NS + (tid - ND)];
    __syncthreads();

    {
        int part = tid >> 7, j = tid & 127;
        int k0 = part * 40;
        float a = 0.0f;
        #pragma unroll 8
        for (int k = k0; k < k0 + 40; k++) a += din[k] * dec_w1[k * NH + j];
        p1[part][j] = a;
    }
    __syncthreads();
    if (tid < NH) {
        float a = dec_b1[tid] + p1[0][tid] + p1[1][tid] + p1[2][tid] + p1[3][tid];
        d1[tid] = siluf(a);
    }
    __syncthreads();

    float se = 0.0f;
    const float* trow = tgt + (size_t)rb * NOBS;
    for (int o = tid; o < NOBS; o += 512) {
        float a = dec_b2[o];
        #pragma unroll 8
        for (int i = 0; i < NH; i++) a += d1[i] * dec_w2[i * NOBS + o];
        float df = a - trow[o];
        se += df * df;
    }
    for (int o = 32; o > 0; o >>= 1) se += __shfl_down(se, o);
    if ((tid & 63) == 0) redb[tid >> 6] = se;
    __syncthreads();
    if (tid == 0) {
        float s = 0.0f;
        for (int p = 0; p < 8; p++) s += redb[p];
        recon_out[rb] = s * (1.0f / 768.0f);
    }
}

// -------- Kernel 5: finalize (mask-weighted scalar combine) --------
__global__ void finalize(const float* __restrict__ maskf,
                         const float* __restrict__ recon,
                         const float* __restrict__ kl,
                         float* __restrict__ out)
{
    if (threadIdx.x != 0 || blockIdx.x != 0) return;
    float rl = 0.0f, rs = 0.0f, ka = 0.0f, kn = 0.0f;
    for (int t = 0; t < NV; t++) {
        float ms = 0.0f, rsum = 0.0f, osum = 0.0f, ksum = 0.0f;
        for (int b = 0; b < NB; b++) {
            float m = maskf[t * NB + b];
            ms += m;
            rsum += recon[t * NB + b] * m;
            osum += 1.0f - m;
            ksum += kl[t * NB + b] * (1.0f - m);
        }
        if (ms > 0.0f) { rl += rsum / fmaxf(ms, 1.0f); rs += 1.0f; }
        if (osum > 0.0f) { ka += ksum / fmaxf(osum, 1.0f); kn += 1.0f; }
    }
    out[0] = rl / fmaxf(rs, 1.0f);
    out[1] = (ka / fmaxf(kn, 1.0f)) * 1e-4f;
}

extern "C" void kernel_launch(void* const* d_in, const int* in_sizes, int n_in,
                              void* d_out, int out_size, void* d_ws, size_t ws_size,
                              hipStream_t stream) {
    const float* sf0 = (const float*)d_in[0];
    const float* sf1 = (const float*)d_in[1];
    const float* tf0 = (const float*)d_in[2];
    const float* tf1 = (const float*)d_in[3];
    const void*  cam = d_in[4];
    const float* eps_prior = (const float*)d_in[5];
    const float* eps_post  = (const float*)d_in[6];
    const float* enc_w1 = (const float*)d_in[7];
    const float* enc_b1 = (const float*)d_in[8];
    const float* ln_g   = (const float*)d_in[9];
    const float* ln_b   = (const float*)d_in[10];
    const float* enc_w2 = (const float*)d_in[11];
    const float* enc_b2 = (const float*)d_in[12];
    const float* prior_w1 = (const float*)d_in[13];
    const float* prior_b1 = (const float*)d_in[14];
    const float* prior_w2 = (const float*)d_in[15];
    const float* prior_b2 = (const float*)d_in[16];
    const float* post_w1 = (const float*)d_in[17];
    const float* post_b1 = (const float*)d_in[18];
    const float* post_w2 = (const float*)d_in[19];
    const float* post_b2 = (const float*)d_in[20];
    const float* dec_w1 = (const float*)d_in[21];
    const float* dec_b1 = (const float*)d_in[22];
    const float* dec_w2 = (const float*)d_in[23];
    const float* dec_b2 = (const float*)d_in[24];
    const float* gru_wih = (const float*)d_in[25];
    const float* gru_whh = (const float*)d_in[26];
    const float* gru_bih = (const float*)d_in[27];
    const float* gru_bhh = (const float*)d_in[28];

    float* ws = (float*)d_ws;
    float* obs   = ws;                 // 48*768 = 36864
    float* tgt   = ws + 36864;         // 36864
    float* oe    = ws + 73728;         // 48*128 = 6144
    float* maskf = ws + 79872;         // 48
    float* rec   = ws + 79920;         // 48
    float* klv   = ws + 79968;         // 48
    float* deter_all = ws + 80016;     // 48*128 = 6144
    float* z_all     = ws + 86160;     // 48*32  = 1536
    float* warm_dummy = ws + 87696;    // 64

    // student reduction: 2048 blocks x 256 = 8192 waves over 18432 jobs
    reduce_obs<<<RWAVES / 4, 256, 0, stream>>>(sf0, sf1, obs);
    // encoder + mask prep + weight warm
    encoder<<<65, 512, 0, stream>>>(obs, enc_w1, enc_b1, ln_g, ln_b, enc_w2, enc_b2, oe,
                                    cam, maskf,
                                    prior_w1, post_w1, prior_w2, post_w2, gru_wih, gru_whh,
                                    warm_dummy);
    // fused: blocks 0-7 spill-free scan, blocks 8..2055 teacher NT reduction
    fused_scan_tgt<<<8 + RWAVES / 4, 256, 0, stream>>>(
                                     oe, maskf, eps_prior, eps_post,
                                     prior_w1, prior_b1, prior_w2, prior_b2,
                                     post_w1, post_b1, post_w2, post_b2,
                                     gru_wih, gru_whh, gru_bih, gru_bhh,
                                     deter_all, z_all, klv,
                                     tf0, tf1, tgt);
    decoder_kernel<<<48, 512, 0, stream>>>(deter_all, z_all, tgt,
                                           dec_w1, dec_b1, dec_w2, dec_b2, rec);
    finalize<<<1, 64, 0, stream>>>(maskf, rec, klv, (float*)d_out);
}